// Round 1
// baseline (377.301 us; speedup 1.0000x reference)
//
#include <hip/hip_runtime.h>

// SSIM3D loss, fully fused: separable 11x11x11 Gaussian conv of 5 fields
// (x, y, x^2, y^2, xy) + SSIM map + global mean, in one pass over the inputs.
//
// Decomposition: block = 512 threads owns a 32(H) x 16(W) tile column and
// streams along D. Per input slice: stage x,y tile (42x26) in LDS, W-conv
// (5 fields at once), H-conv to registers, D-conv via an 11-deep register
// ring (statically indexed). Prefetch next slice during compute.

#define BATCH 2
#define DD 128
#define HH 256
#define WW 256
#define TH 32
#define TW 16
#define KS 11
#define HALO 5
#define XH (TH + 2*HALO)      // 42
#define XW (TW + 2*HALO)      // 26
#define XSTR 48               // padded row stride: 48 % 32 == 16 -> 2-way LDS aliasing (free)
#define NTHREADS 512
#define C1F 1.0e-4f
#define C2F 9.0e-4f
#define NVOX (2.0 * 128.0 * 256.0 * 256.0)

// init: zero the double accumulator, extract separable g[11] from the 11^3 window.
// window[i][j][k] = g_i*g_j*g_k with sum(g)=1  =>  g_i = sum_{j,k} window[i][j][k]
__global__ void ssim_init_kernel(const float* __restrict__ win,
                                 double* __restrict__ acc,
                                 float* __restrict__ g) {
    int i = threadIdx.x;
    if (i == 0) acc[0] = 0.0;
    if (i < KS) {
        float s = 0.f;
        #pragma unroll 1
        for (int j = 0; j < KS * KS; ++j) s += win[i * KS * KS + j];
        g[i] = s;
    }
}

__global__ __launch_bounds__(NTHREADS, 2)
void ssim_main_kernel(const float* __restrict__ img1,
                      const float* __restrict__ img2,
                      const float* __restrict__ gcoef,
                      double* __restrict__ acc) {
    __shared__ float xt[XH * XSTR];
    __shared__ float yt[XH * XSTR];
    __shared__ float wb[5][XH * TW];      // W-convolved fields, rows incl. H-halo
    __shared__ double red[NTHREADS / 64];

    const int tid = threadIdx.x;
    const int tx = tid & (TW - 1);
    const int ty = tid >> 4;              // 0..31
    const int w0 = blockIdx.x * TW;
    const int h0 = blockIdx.y * TH;
    const int b  = blockIdx.z;

    const size_t plane = (size_t)HH * WW;
    const float* base1 = img1 + (size_t)b * DD * plane;
    const float* base2 = img2 + (size_t)b * DD * plane;

    float g[KS];
    #pragma unroll
    for (int i = 0; i < KS; ++i) g[i] = gcoef[i];

    // D-direction ring buffer of in-plane-convolved values, 5 fields x 11 slices.
    // All indices compile-time constant (full unroll) -> stays in VGPRs.
    float ring[5][KS];
    #pragma unroll
    for (int f = 0; f < 5; ++f)
        #pragma unroll
        for (int i = 0; i < KS; ++i) ring[f][i] = 0.f;

    float pv1[3], pv2[3];

    // prefetch slice 0
    #pragma unroll
    for (int s = 0; s < 3; ++s) {
        int p = tid + s * NTHREADS;
        float v1 = 0.f, v2 = 0.f;
        if (p < XH * XW) {
            int r = p / XW;
            int c = p - r * XW;
            int gh = h0 - HALO + r;
            int gw = w0 - HALO + c;
            if ((unsigned)gh < HH && (unsigned)gw < WW) {
                size_t off = (size_t)gh * WW + gw;   // dIn = 0
                v1 = base1[off];
                v2 = base2[off];
            }
        }
        pv1[s] = v1; pv2[s] = v2;
    }

    double lsum = 0.0;

    for (int dIn = -HALO; dIn <= DD + HALO - 1; ++dIn) {
        // shift ring (register renames after unroll)
        #pragma unroll
        for (int f = 0; f < 5; ++f)
            #pragma unroll
            for (int i = 0; i < KS - 1; ++i) ring[f][i] = ring[f][i + 1];

        float s0 = 0.f, s1 = 0.f, s2 = 0.f, s3 = 0.f, s4 = 0.f;

        if ((unsigned)dIn < DD) {          // block-uniform branch: barriers legal
            // commit prefetched slice to LDS (compiler waits vmcnt here)
            #pragma unroll
            for (int s = 0; s < 3; ++s) {
                int p = tid + s * NTHREADS;
                if (p < XH * XW) {
                    int r = p / XW;
                    int c = p - r * XW;
                    xt[r * XSTR + c] = pv1[s];
                    yt[r * XSTR + c] = pv2[s];
                }
            }
            __syncthreads();   // xt/yt ready; also fences prev Hconv wb reads vs this Wconv writes

            // issue prefetch for next slice; lands during Wconv/Hconv/emit
            if (dIn + 1 < DD) {
                #pragma unroll
                for (int s = 0; s < 3; ++s) {
                    int p = tid + s * NTHREADS;
                    float v1 = 0.f, v2 = 0.f;
                    if (p < XH * XW) {
                        int r = p / XW;
                        int c = p - r * XW;
                        int gh = h0 - HALO + r;
                        int gw = w0 - HALO + c;
                        if ((unsigned)gh < HH && (unsigned)gw < WW) {
                            size_t off = (size_t)(dIn + 1) * plane + (size_t)gh * WW + gw;
                            v1 = base1[off];
                            v2 = base2[off];
                        }
                    }
                    pv1[s] = v1; pv2[s] = v2;
                }
            }

            // W-conv: 42 rows x 16 output cols, all 5 fields per LDS read pair
            for (int p = tid; p < XH * TW; p += NTHREADS) {
                int r = p >> 4;
                int c = p & (TW - 1);
                const float* xrow = &xt[r * XSTR + c];
                const float* yrow = &yt[r * XSTR + c];
                float a0 = 0.f, a1 = 0.f, a2 = 0.f, a3 = 0.f, a4 = 0.f;
                #pragma unroll
                for (int k = 0; k < KS; ++k) {
                    float xv = xrow[k], yv = yrow[k], gk = g[k];
                    a0 += gk * xv;
                    a1 += gk * yv;
                    a2 += gk * xv * xv;
                    a3 += gk * yv * yv;
                    a4 += gk * xv * yv;
                }
                wb[0][p] = a0; wb[1][p] = a1; wb[2][p] = a2; wb[3][p] = a3; wb[4][p] = a4;
            }
            __syncthreads();   // wb ready; also fences this Wconv xt reads vs next LDS commit

            // H-conv: one output position per thread
            #pragma unroll
            for (int r2 = 0; r2 < KS; ++r2) {
                int o = (ty + r2) * TW + tx;
                float gr = g[r2];
                s0 += gr * wb[0][o];
                s1 += gr * wb[1][o];
                s2 += gr * wb[2][o];
                s3 += gr * wb[3][o];
                s4 += gr * wb[4][o];
            }
        }

        ring[0][KS-1] = s0; ring[1][KS-1] = s1; ring[2][KS-1] = s2;
        ring[3][KS-1] = s3; ring[4][KS-1] = s4;

        // emit output slice dIn-5: D-conv over the ring + SSIM map
        int dout = dIn - HALO;
        if ((unsigned)dout < DD) {
            float m1 = 0.f, m2 = 0.f, exx = 0.f, eyy = 0.f, exy = 0.f;
            #pragma unroll
            for (int i = 0; i < KS; ++i) {
                float gi = g[i];
                m1  += gi * ring[0][i];
                m2  += gi * ring[1][i];
                exx += gi * ring[2][i];
                eyy += gi * ring[3][i];
                exy += gi * ring[4][i];
            }
            float mu11 = m1 * m1, mu22 = m2 * m2, mu12 = m1 * m2;
            float sg1  = exx - mu11;
            float sg2  = eyy - mu22;
            float sg12 = exy - mu12;
            float num = (2.f * mu12 + C1F) * (2.f * sg12 + C2F);
            float den = (mu11 + mu22 + C1F) * (sg1 + sg2 + C2F);
            lsum += (double)(num / den);
        }
    }

    // block reduction: wave shuffle -> LDS -> one f64 atomic per block
    #pragma unroll
    for (int off = 32; off > 0; off >>= 1)
        lsum += __shfl_down(lsum, off, 64);
    int lane = tid & 63, wid = tid >> 6;
    if (lane == 0) red[wid] = lsum;
    __syncthreads();
    if (tid == 0) {
        double bsum = 0.0;
        #pragma unroll
        for (int wv = 0; wv < NTHREADS / 64; ++wv) bsum += red[wv];
        atomicAdd(acc, bsum);
    }
}

__global__ void ssim_fin_kernel(const double* __restrict__ acc,
                                float* __restrict__ out) {
    out[0] = (float)(1.0 - acc[0] / NVOX);
}

extern "C" void kernel_launch(void* const* d_in, const int* in_sizes, int n_in,
                              void* d_out, int out_size, void* d_ws, size_t ws_size,
                              hipStream_t stream) {
    const float* img1 = (const float*)d_in[0];
    const float* img2 = (const float*)d_in[1];
    const float* win  = (const float*)d_in[2];
    double* acc = (double*)d_ws;
    float*  g   = (float*)((char*)d_ws + 16);

    hipLaunchKernelGGL(ssim_init_kernel, dim3(1), dim3(64), 0, stream, win, acc, g);
    hipLaunchKernelGGL(ssim_main_kernel, dim3(WW / TW, HH / TH, BATCH), dim3(NTHREADS),
                       0, stream, img1, img2, g, acc);
    hipLaunchKernelGGL(ssim_fin_kernel, dim3(1), dim3(1), 0, stream, acc, (float*)d_out);
}